// Round 3
// baseline (2961.684 us; speedup 1.0000x reference)
//
#include <hip/hip_runtime.h>

typedef unsigned int u32;
typedef unsigned short u16;
typedef _Float16 f16x2 __attribute__((ext_vector_type(2)));

// ---------------- problem constants ----------------
// B=32, T=32, F=64, H=256, N=1024, A=64, C=192, M=256
// out: hs [32,256,32] (262144 f32) then outs [32,10,32] (10240 f32)

// ---------------- workspace (u32 offsets) ----------------
#define WP_A0    0        // [160][256] u32 pairs: [Wh0;Wi0]^T f16-pairs over k
#define WP_A1    40960    // [160][256]
#define WP_A2H   81920    // [128][256] Wh2^T
#define WP_A2I   114688   // [32][256]  Wi2^T
#define WP_AQ    122880   // [128][256] Wq^T
#define WP_AC    155648   // [160][192] [Wch;Wci]^T
#define WP_AM    186368   // 3 x [128][256] Wm^T
#define WP_MP2   284672   // [512][64]  maddr n-pairs f16
#define WP_ADDRT 317440   // f32 [64][1024] maddr^T

// ---------------- LDS layout (float offsets) ----------------
#define SH_HX   0      // f32 h[256]
#define SH_H2   256    // u32[160] (h,x) f16 pairs
#define SH_Q    416    // f32 q[256] (incl bq)
#define SH_GA0  672    // f32 [3][256]
#define SH_GA1  1440   // f32 [3][256]
#define SH_GH2  2208   // f32 [2][256]
#define SH_GI2  2720   // f32 [256]
#define SH_GM   2976   // f32 [12][256]
#define SH_SIMA 6048   // f32 [1024]
#define SH_R2   7072   // u32 [128] reading f16 pairs
#define SH_D    7200   // f32 [32]
#define SH_G    7232   // f32 [32]
#define SH_RED  7264   // f32 [16]
#define SH_RED2 7280   // f32 [16]
#define SH_MISC 7296   // f32 [8]  [0]=beta
#define SH_B10  7304   // f32 [16]
#define SH_RA   7320   // f32 [8][64] reading_a partials
#define SH_CAND 7832   // u16[32*192] = 6144 u16 = 3072 f32 slots
#define SH_W    10904  // u16[32][1024] (16384 f32 slots)  -- was 9368: OVERLAP BUG
#define SMEM_FLOATS 27288
#define SMEM_BYTES (SMEM_FLOATS*4)

#define WRED(v) { v += __shfl_xor(v,32); v += __shfl_xor(v,16); v += __shfl_xor(v,8); \
                  v += __shfl_xor(v,4);  v += __shfl_xor(v,2);  v += __shfl_xor(v,1); }

__device__ __forceinline__ f16x2 bch2(u32 u) { return __builtin_bit_cast(f16x2, u); }

#if __has_builtin(__builtin_amdgcn_fdot2)
__device__ __forceinline__ float FDOT2(f16x2 a, f16x2 b, float c) {
  return __builtin_amdgcn_fdot2(a, b, c, false);
}
#else
__device__ __forceinline__ float FDOT2(f16x2 a, f16x2 b, float c) {
  return c + (float)a[0]*(float)b[0] + (float)a[1]*(float)b[1];
}
#endif

__device__ __forceinline__ u16 f2h(float x) {
  _Float16 h = (_Float16)x; return __builtin_bit_cast(u16, h);
}
__device__ __forceinline__ float h2f(u16 u) {
  return (float)__builtin_bit_cast(_Float16, u);
}
__device__ __forceinline__ u32 packh2(float lo, float hi) {
  return (u32)f2h(lo) | ((u32)f2h(hi) << 16);
}

// ---- k-split matvec: 4 outs/lane (o=ln*4..+3), NP pairs, W2/c2 pre-offset ----
template<int NP>
__device__ __forceinline__ void mv_ks(const u32* __restrict__ W2,
    const u32* __restrict__ c2, float* __restrict__ dst, const int ln)
{
  const u32* wp = W2 + ln * 4;
  float a0=0.f, a1=0.f, a2=0.f, a3=0.f;
  uint4 wA[8], wB[8]; u32 cA[8], cB[8];
  #pragma unroll
  for (int i = 0; i < 8; ++i) { wA[i] = *(const uint4*)(wp + i*256); cA[i] = c2[i]; }
  #pragma unroll
  for (int p = 0; p < NP; p += 16) {
    if (p + 8 < NP) {
      #pragma unroll
      for (int i = 0; i < 8; ++i) { wB[i] = *(const uint4*)(wp + (p+8+i)*256); cB[i] = c2[p+8+i]; }
    }
    #pragma unroll
    for (int i = 0; i < 8; ++i) {
      const f16x2 c = bch2(cA[i]);
      a0 = FDOT2(bch2(wA[i].x), c, a0);
      a1 = FDOT2(bch2(wA[i].y), c, a1);
      a2 = FDOT2(bch2(wA[i].z), c, a2);
      a3 = FDOT2(bch2(wA[i].w), c, a3);
    }
    if (p + 16 < NP) {
      #pragma unroll
      for (int i = 0; i < 8; ++i) { wA[i] = *(const uint4*)(wp + (p+16+i)*256); cA[i] = c2[p+16+i]; }
    }
    if (p + 8 < NP) {
      #pragma unroll
      for (int i = 0; i < 8; ++i) {
        const f16x2 c = bch2(cB[i]);
        a0 = FDOT2(bch2(wB[i].x), c, a0);
        a1 = FDOT2(bch2(wB[i].y), c, a1);
        a2 = FDOT2(bch2(wB[i].z), c, a2);
        a3 = FDOT2(bch2(wB[i].w), c, a3);
      }
    }
  }
  *(float4*)(dst + ln*4) = make_float4(a0, a1, a2, a3);
}

// ---- out-split matvec core: 1 out/lane (W2 pre-offset by obase), full NP pairs ----
template<int NP, int LD>
__device__ __forceinline__ float mv_os(const u32* __restrict__ W2,
    const u32* __restrict__ c2, const int ln)
{
  const u32* wp = W2 + ln;
  float a = 0.f;
  u32 wA[16], wB[16], cA[16], cB[16];
  #pragma unroll
  for (int i = 0; i < 16; ++i) { wA[i] = wp[i*LD]; cA[i] = c2[i]; }
  #pragma unroll
  for (int p = 0; p < NP; p += 32) {
    if (p + 16 < NP) {
      #pragma unroll
      for (int i = 0; i < 16; ++i) { wB[i] = wp[(p+16+i)*LD]; cB[i] = c2[p+16+i]; }
    }
    #pragma unroll
    for (int i = 0; i < 16; ++i) a = FDOT2(bch2(wA[i]), bch2(cA[i]), a);
    if (p + 32 < NP) {
      #pragma unroll
      for (int i = 0; i < 16; ++i) { wA[i] = wp[(p+32+i)*LD]; cA[i] = c2[p+32+i]; }
    }
    if (p + 16 < NP) {
      #pragma unroll
      for (int i = 0; i < 16; ++i) a = FDOT2(bch2(wB[i]), bch2(cB[i]), a);
    }
  }
  return a;
}

__device__ __forceinline__ void out_lse(const float* __restrict__ b10,
    float* __restrict__ out, const int t_out, const int bb, const int ln)
{
  float v = (ln < 10) ? b10[ln] : -1e30f;
  float m = v;
  m = fmaxf(m, __shfl_xor(m, 8, 16));
  m = fmaxf(m, __shfl_xor(m, 4, 16));
  m = fmaxf(m, __shfl_xor(m, 2, 16));
  m = fmaxf(m, __shfl_xor(m, 1, 16));
  float e = (ln < 10) ? __expf(v - m) : 0.f;
  float s = e;
  s += __shfl_xor(s, 8, 16);
  s += __shfl_xor(s, 4, 16);
  s += __shfl_xor(s, 2, 16);
  s += __shfl_xor(s, 1, 16);
  if (ln < 10) out[262144 + t_out * 320 + ln * 32 + bb] = v - m - logf(s);
}

// ---------------- pack kernel: f16 pair-packed transposed weights ----------------
__global__ void pack_weights(const float* __restrict__ Wi, const float* __restrict__ Wh,
                             const float* __restrict__ Wm, const float* __restrict__ Wq,
                             const float* __restrict__ Wch, const float* __restrict__ Wci,
                             const float* __restrict__ maddr, u32* __restrict__ wsu)
{
  const int b = blockIdx.x, tid = threadIdx.x;
  if (b >= 155) {  // MP2: maddr n-pairs f16, [512][64]
    const int pb = (b - 155) * 64;
    const int a = tid & 63, pq = tid >> 6;
    for (int pp = pq; pp < 64; pp += 4) {
      const int p = pb + pp;
      wsu[WP_MP2 + p*64 + a] = packh2(maddr[(2*p)*64 + a], maddr[(2*p+1)*64 + a]);
    }
    return;
  }
  __shared__ float tile[64][65];
  const int c = tid & 63, r4 = tid >> 6;
  if (b >= 139) {  // addrT f32 [64][1024]
    float* dst = (float*)(wsu + WP_ADDRT);
    const int tr = b - 139;
    #pragma unroll 4
    for (int it = 0; it < 16; ++it) {
      const int r = it*4 + r4;
      tile[r][c] = maddr[(size_t)(tr*64 + r)*64 + c];
    }
    __syncthreads();
    #pragma unroll 4
    for (int it = 0; it < 16; ++it) {
      const int rr = it*4 + r4;
      dst[(size_t)rr * 1024 + tr*64 + c] = tile[c][rr];
    }
    return;
  }
  const float* src; u32* dst; int Ksrc, srck, P0, ld, tr, tk;
  if (b < 20)       { int x=b;    tr=x/5; tk=x%5; ld=256; dst=wsu+WP_A0;
                      src=(tk<4)? Wh : Wi;              Ksrc=(tk<4)?256:64; srck=(tk<4)?tk*64:0; P0=tk*32; }
  else if (b < 40)  { int x=b-20; tr=x/5; tk=x%5; ld=256; dst=wsu+WP_A1;
                      src=(tk<4)? Wh+65536 : Wi+16384;  Ksrc=(tk<4)?256:64; srck=(tk<4)?tk*64:0; P0=tk*32; }
  else if (b < 56)  { int x=b-40; tr=x/4; tk=x%4; ld=256; dst=wsu+WP_A2H;
                      src=Wh+131072; Ksrc=256; srck=tk*64; P0=tk*32; }
  else if (b < 60)  { int x=b-56; tr=x;   tk=0;   ld=256; dst=wsu+WP_A2I;
                      src=Wi+32768;  Ksrc=64;  srck=0;     P0=0; }
  else if (b < 76)  { int x=b-60; tr=x/4; tk=x%4; ld=256; dst=wsu+WP_AQ;
                      src=Wq; Ksrc=256; srck=tk*64; P0=tk*32; }
  else if (b < 91)  { int x=b-76; tr=x/5; tk=x%5; ld=192; dst=wsu+WP_AC;
                      src=(tk<4)? Wch : Wci; Ksrc=(tk<4)?256:64; srck=(tk<4)?tk*64:0; P0=tk*32; }
  else              { int x=b-91; int g=x/16, r5=x%16; tr=r5/4; tk=r5%4; ld=256;
                      dst=wsu+WP_AM + g*32768; src=Wm + g*65536; Ksrc=256; srck=tk*64; P0=tk*32; }
  #pragma unroll 4
  for (int it = 0; it < 16; ++it) {
    const int r = it*4 + r4;  // o-local
    tile[r][c] = src[(size_t)(tr*64 + r)*Ksrc + srck + c];  // tile[o][k]
  }
  __syncthreads();
  for (int pp = r4; pp < 32; pp += 4) {
    dst[(size_t)(P0 + pp)*ld + tr*64 + c] = packh2(tile[c][2*pp], tile[c][2*pp+1]);
  }
}

// ---------------- main persistent per-batch kernel ----------------
__global__ __launch_bounds__(1024, 4) void dntm_step(
    const float* __restrict__ batch, const float* __restrict__ bi,
    const float* __restrict__ bh, const float* __restrict__ bm,
    const float* __restrict__ Wo, const float* __restrict__ bo,
    const float* __restrict__ maddr, const float* __restrict__ bq,
    const float* __restrict__ usharp, const u32* __restrict__ wsu,
    float* __restrict__ out)
{
  extern __shared__ float sm[];
  u32* h2u  = (u32*)(sm + SH_H2);
  u32* R2u  = (u32*)(sm + SH_R2);
  u16* candh = (u16*)(sm + SH_CAND);
  u16* SW16 = (u16*)(sm + SH_W);
  u32* SW32 = (u32*)(sm + SH_W);
  const float* addrT = (const float*)(wsu + WP_ADDRT);
  const int tid = threadIdx.x, ln = tid & 63, wv = tid >> 6;
  const int bb = blockIdx.x;

  // init: h = 0 (f32 + pairs), load x_0 pairs
  if (tid < 256) sm[SH_HX + tid] = 0.f;
  if (tid < 128) h2u[tid] = 0u;
  if (tid >= 128 && tid < 160) {
    const int j = tid - 128;
    const int i0 = (2*j)*32 + bb, i1 = i0 + 32;
    const float x0 = batch[(i0 >> 6)*2048 + (i0 & 63)];
    const float x1 = batch[(i1 >> 6)*2048 + (i1 & 63)];
    h2u[128 + j] = packh2(x0, x1);
  }
  __syncthreads();

  for (int t = 0; t < 32; ++t) {
    // ================= P1: all h/x matvecs (f16 dot2) =================
    switch (wv) {
      case 0:  mv_ks<64>(wsu+WP_A0,            h2u,     sm+SH_GA0,     ln); break;
      case 1:  mv_ks<48>(wsu+WP_A0 + 64*256,   h2u+64,  sm+SH_GA0+256, ln); break;
      case 2:  mv_ks<48>(wsu+WP_A0 + 112*256,  h2u+112, sm+SH_GA0+512, ln); break;
      case 3:  mv_ks<64>(wsu+WP_A1,            h2u,     sm+SH_GA1,     ln); break;
      case 4:  mv_ks<48>(wsu+WP_A1 + 64*256,   h2u+64,  sm+SH_GA1+256, ln); break;
      case 5:  mv_ks<48>(wsu+WP_A1 + 112*256,  h2u+112, sm+SH_GA1+512, ln); break;
      case 6:  mv_ks<64>(wsu+WP_A2H,           h2u,     sm+SH_GH2,     ln); break;
      case 7:  mv_ks<64>(wsu+WP_A2H + 64*256,  h2u+64,  sm+SH_GH2+256, ln); break;
      case 8: case 9: case 10: case 11: {
        const int ob = (wv - 8) * 64;
        const float a = mv_os<128,256>(wsu+WP_AQ + ob, h2u, ln);
        sm[SH_Q + ob + ln] = a + bq[ob + ln];
      } break;
      case 12: {
        mv_ks<32>(wsu+WP_A2I, h2u+128, sm+SH_GI2, ln);
        // beta = softplus(u.h) + 1
        const float4 h4 = *(const float4*)(sm + SH_HX + ln*4);
        const float4 u4 = *(const float4*)(usharp + ln*4);
        float v = h4.x*u4.x + h4.y*u4.y + h4.z*u4.z + h4.w*u4.w;
        WRED(v);
        if (!ln) sm[SH_MISC] = fmaxf(v, 0.f) + log1pf(expf(-fabsf(v))) + 1.f;
        // logits of h_t == h_new(t-1)
        if (t > 0) {
          for (int j = 0; j < 10; ++j) {
            const float4 wo = *(const float4*)(Wo + j*256 + ln*4);
            float lv = wo.x*h4.x + wo.y*h4.y + wo.z*h4.z + wo.w*h4.w;
            WRED(lv);
            if (!ln) sm[SH_B10 + j] = lv + bo[j];
          }
        }
      } break;
      default: {  // 13,14,15: cand = relu(Wch h + Wci x) -> f16 history
        const int ob = (wv - 13) * 64;
        const float a = mv_os<160,192>(wsu+WP_AC + ob, h2u, ln);
        candh[t*192 + ob + ln] = f2h(fmaxf(a, 0.f));
      } break;
    }
    __syncthreads();

    // ===== P2: sim addr-part (f32), d[s] = cand_s . q_c, out_lse(t-1) =====
    if (wv < 8) {
      const int n0 = wv * 128;
      const float* at = addrT + n0 + ln*2;
      float ax = 0.f, ay = 0.f;
      #pragma unroll 4
      for (int a = 0; a < 64; a += 4) {
        const float4 q4 = *(const float4*)(sm + SH_Q + a);
        const float2 r0 = *(const float2*)(at + (a+0)*1024);
        const float2 r1 = *(const float2*)(at + (a+1)*1024);
        const float2 r2 = *(const float2*)(at + (a+2)*1024);
        const float2 r3 = *(const float2*)(at + (a+3)*1024);
        ax = fmaf(q4.x, r0.x, ax); ay = fmaf(q4.x, r0.y, ay);
        ax = fmaf(q4.y, r1.x, ax); ay = fmaf(q4.y, r1.y, ay);
        ax = fmaf(q4.z, r2.x, ax); ay = fmaf(q4.z, r2.y, ay);
        ax = fmaf(q4.w, r3.x, ax); ay = fmaf(q4.w, r3.y, ay);
      }
      *(float2*)(sm + SH_SIMA + n0 + ln*2) = make_float2(ax, ay);
    } else if (wv < 15) {
      const float q0 = sm[SH_Q + 64 + ln], q1 = sm[SH_Q + 128 + ln], q2 = sm[SH_Q + 192 + ln];
      for (int s = wv - 8; s < t; s += 7) {
        float a2 = h2f(candh[s*192 + ln]) * q0
                 + h2f(candh[s*192 + 64 + ln]) * q1
                 + h2f(candh[s*192 + 128 + ln]) * q2;
        WRED(a2);
        if (!ln) sm[SH_D + s] = a2;
      }
    } else {
      if (t > 0) out_lse(sm + SH_B10, out, t - 1, bb, ln);
    }
    __syncthreads();

    // ===== P3: v = beta*(sim_a + sum_s d[s] w_s[n]); wave max (v stays in regs) =====
    const int n3 = wv * 64 + ln;
    float v = sm[SH_SIMA + n3];
    #pragma unroll 4
    for (int s = 0; s < t; ++s) v = fmaf(sm[SH_D + s], h2f(SW16[s*1024 + n3]), v);
    v *= sm[SH_MISC];
    {
      float mx = v;
      mx = fmaxf(mx, __shfl_xor(mx, 32)); mx = fmaxf(mx, __shfl_xor(mx, 16));
      mx = fmaxf(mx, __shfl_xor(mx, 8));  mx = fmaxf(mx, __shfl_xor(mx, 4));
      mx = fmaxf(mx, __shfl_xor(mx, 2));  mx = fmaxf(mx, __shfl_xor(mx, 1));
      if (!ln) sm[SH_RED + wv] = mx;
    }
    __syncthreads();

    // ===== P4: e = exp(v - gmax) -> f16 history row t (unnormalized); wave sums =====
    {
      float gmx = sm[SH_RED];
      #pragma unroll
      for (int i = 1; i < 16; ++i) gmx = fmaxf(gmx, sm[SH_RED + i]);
      const float e = __expf(v - gmx);
      SW16[t*1024 + n3] = f2h(e);
      float s2 = e; WRED(s2);
      if (!ln) sm[SH_RED2 + wv] = s2;
    }
    __syncthreads();

    // ===== P5: reading_a partials (f16 dot2 vs maddr pairs); g[s] = w_s . w_t =====
    {
      float tot = 0.f;
      #pragma unroll
      for (int i = 0; i < 16; ++i) tot += sm[SH_RED2 + i];
      const float inv = 1.0f / tot;
      if (wv < 8) {
        const int p0 = wv * 64;  // n-pair base
        const u32* mp = wsu + WP_MP2 + (size_t)p0*64 + ln;
        float acc = 0.f;
        #pragma unroll 8
        for (int pp = 0; pp < 64; ++pp) {
          const u32 e2 = SW32[t*512 + p0 + pp];
          acc = FDOT2(bch2(mp[pp*64]), bch2(e2), acc);
        }
        sm[SH_RA + wv*64 + ln] = acc * inv;
      } else {
        const uint4 ea = *(const uint4*)(SW32 + t*512 + ln*8);
        const uint4 eb = *(const uint4*)(SW32 + t*512 + ln*8 + 4);
        for (int s = wv - 8; s < t; s += 8) {
          const uint4 wa = *(const uint4*)(SW32 + s*512 + ln*8);
          const uint4 wb = *(const uint4*)(SW32 + s*512 + ln*8 + 4);
          float a2 = 0.f;
          a2 = FDOT2(bch2(ea.x), bch2(wa.x), a2);
          a2 = FDOT2(bch2(ea.y), bch2(wa.y), a2);
          a2 = FDOT2(bch2(ea.z), bch2(wa.z), a2);
          a2 = FDOT2(bch2(ea.w), bch2(wa.w), a2);
          a2 = FDOT2(bch2(eb.x), bch2(wb.x), a2);
          a2 = FDOT2(bch2(eb.y), bch2(wb.y), a2);
          a2 = FDOT2(bch2(eb.z), bch2(wb.z), a2);
          a2 = FDOT2(bch2(eb.w), bch2(wb.w), a2);
          WRED(a2);
          if (!ln) sm[SH_G + s] = a2 * inv;
        }
      }
    }
    __syncthreads();

    // ===== P6: assemble reading -> f16 pairs R2 =====
    if (wv == 0) {
      float r = 0.f;
      #pragma unroll
      for (int j = 0; j < 8; ++j) r += sm[SH_RA + j*64 + ln];
      const float rh = __shfl_down(r, 1);
      if (!(ln & 1)) R2u[ln >> 1] = packh2(r, rh);
    } else if (wv < 4) {
      const int c = (wv - 1)*64 + ln;
      float r = 0.f;
      for (int s = 0; s < t; ++s) r = fmaf(h2f(candh[s*192 + c]), sm[SH_G + s], r);
      const float rh = __shfl_down(r, 1);
      if (!(ln & 1)) R2u[wv*32 + (ln >> 1)] = packh2(r, rh);
    }
    __syncthreads();

    // ===== P7: gm = Wm @ reading (12 waves); normalize w row t; prefetch x_{t+1} =====
    if (wv < 12) {
      const int g = wv >> 2, qt = wv & 3;
      mv_ks<32>(wsu + WP_AM + g*32768 + qt*32*256, R2u + qt*32, sm + SH_GM + wv*256, ln);
    } else if (wv < 14) {
      float tot = 0.f;
      #pragma unroll
      for (int i = 0; i < 16; ++i) tot += sm[SH_RED2 + i];
      const float inv = 1.0f / tot;
      u32* p = SW32 + t*512 + (wv - 12)*256 + ln*4;
      uint4 v4 = *(const uint4*)p;
      v4.x = packh2(h2f(v4.x & 0xffff)*inv, h2f(v4.x >> 16)*inv);
      v4.y = packh2(h2f(v4.y & 0xffff)*inv, h2f(v4.y >> 16)*inv);
      v4.z = packh2(h2f(v4.z & 0xffff)*inv, h2f(v4.z >> 16)*inv);
      v4.w = packh2(h2f(v4.w & 0xffff)*inv, h2f(v4.w >> 16)*inv);
      *(uint4*)p = v4;
    } else if (wv == 14) {
      if (t < 31 && ln < 32) {
        const int i0 = (2*ln)*32 + bb, i1 = i0 + 32;
        const float x0 = batch[(i0 >> 6)*2048 + (t+1)*64 + (i0 & 63)];
        const float x1 = batch[(i1 >> 6)*2048 + (t+1)*64 + (i1 & 63)];
        h2u[128 + ln] = packh2(x0, x1);
      }
    }
    __syncthreads();

    // ===== P8: gate combine, h update, hs output, pack h pairs =====
    if (tid < 256) {
      const int h = tid;
      const float gm0 = sm[SH_GM+h]        + sm[SH_GM+256+h]  + sm[SH_GM+512+h]  + sm[SH_GM+768+h]  + bm[h];
      const float gm1 = sm[SH_GM+1024+h]   + sm[SH_GM+1280+h] + sm[SH_GM+1536+h] + sm[SH_GM+1792+h] + bm[256+h];
      const float gm2 = sm[SH_GM+2048+h]   + sm[SH_GM+2304+h] + sm[SH_GM+2560+h] + sm[SH_GM+2816+h] + bm[512+h];
      const float g0  = sm[SH_GA0+h] + sm[SH_GA0+256+h] + sm[SH_GA0+512+h] + bh[h]     + bi[h]     + gm0;
      const float g1  = sm[SH_GA1+h] + sm[SH_GA1+256+h] + sm[SH_GA1+512+h] + bh[256+h] + bi[256+h] + gm1;
      const float gh2v = sm[SH_GH2+h] + sm[SH_GH2+256+h] + bh[512+h];
      const float gi2v = sm[SH_GI2+h] + bi[512+h];
      const float r = 1.f / (1.f + __expf(-g0));
      const float z = 1.f / (1.f + __expf(-g1));
      const float nn = tanhf(gi2v + gm2 + r * gh2v);
      const float hn = (1.f - z) * nn + z * sm[SH_HX + h];
      sm[SH_HX + h] = hn;
      out[t*8192 + h*32 + bb] = hn;
      const float hn1 = __shfl_down(hn, 1);
      if (!(tid & 1)) h2u[tid >> 1] = packh2(hn, hn1);
    }
    __syncthreads();
  }

  // ---- epilogue: out[31] ----
  if (wv == 0) {
    const float4 h4 = *(const float4*)(sm + SH_HX + ln*4);
    for (int j = 0; j < 10; ++j) {
      const float4 wo = *(const float4*)(Wo + j*256 + ln*4);
      float lv = wo.x*h4.x + wo.y*h4.y + wo.z*h4.z + wo.w*h4.w;
      WRED(lv);
      if (!ln) sm[SH_B10 + j] = lv + bo[j];
    }
    out_lse(sm + SH_B10, out, 31, bb, ln);
  }
}

extern "C" void kernel_launch(void* const* d_in, const int* in_sizes, int n_in,
                              void* d_out, int out_size, void* d_ws, size_t ws_size,
                              hipStream_t stream) {
  (void)in_sizes; (void)n_in; (void)out_size; (void)ws_size;
  const float* batch = (const float*)d_in[0];
  const float* Wi    = (const float*)d_in[1];
  const float* bi    = (const float*)d_in[2];
  const float* Wh    = (const float*)d_in[3];
  const float* bh    = (const float*)d_in[4];
  const float* Wm    = (const float*)d_in[5];
  const float* bm    = (const float*)d_in[6];
  const float* Wo    = (const float*)d_in[7];
  const float* bo    = (const float*)d_in[8];
  const float* maddr = (const float*)d_in[9];
  const float* Wq    = (const float*)d_in[10];
  const float* bq    = (const float*)d_in[11];
  const float* us    = (const float*)d_in[12];
  const float* Wch   = (const float*)d_in[13];
  const float* Wci   = (const float*)d_in[14];
  u32* wsu  = (u32*)d_ws;
  float* out = (float*)d_out;

  hipFuncSetAttribute((const void*)dntm_step,
                      hipFuncAttributeMaxDynamicSharedMemorySize, 163840);

  pack_weights<<<163, 256, 0, stream>>>(Wi, Wh, Wm, Wq, Wch, Wci, maddr, wsu);
  dntm_step<<<32, 1024, SMEM_BYTES, stream>>>(batch, bi, bh, bm, Wo, bo, maddr,
                                              bq, us, wsu, out);
}

// Round 4
// 585.084 us; speedup vs baseline: 5.0620x; 5.0620x over previous
//
#include <hip/hip_runtime.h>

typedef unsigned int u32;
typedef unsigned short u16;
typedef _Float16 f16x2 __attribute__((ext_vector_type(2)));

// ---------------- problem constants ----------------
// B=32, T=32, F=64, H=256, N=1024, A=64, C=192, M=256
// out: hs [32,256,32] (262144 f32) then outs [32,10,32] (10240 f32)

// ---------------- workspace (u32 offsets), all k4-packed uint4 [panel][k4][64] ----------------
#define WP_A0    0        // [Wh0;Wi0] 4 panels x 40 k4   (pairs: h 0..127, x 128..159)
#define WP_A1    40960
#define WP_A2H   81920    // Wh2 4 x 32
#define WP_A2I   114688   // Wi2 4 x 8
#define WP_AQ    122880   // Wq  4 x 32
#define WP_AC    155648   // [Wch;Wci] 3 x 40
#define WP_AM    186368   // Wm  12 x 32 (gate-major)
#define WP_AT2   284672   // maddr row-pairs: 16 panels x 8 k4 (outs n, k a)
#define WP_M4    317440   // maddr col view: [128 k4][64 a]  (outs a, k n-pairs)
#define WP_WO4   350208   // W_output: [10][32] uint4

// ---------------- LDS layout (f32 offsets) ----------------
#define SH_HX   0      // f32 h[256]
#define SH_H2   256    // u32[160] (h,x) f16 pairs
#define SH_Q    416    // f32 q[256] (incl bq)
#define SH_Q2   672    // u32[32]  q[0..63] f16 pairs
#define SH_GA0  704    // f32 [256]
#define SH_GA1  960    // f32 [256]
#define SH_GH2  1216   // f32 [256]
#define SH_GI2  1472   // f32 [256]
#define SH_GM   1728   // f32 [3][256]
#define SH_SIMA 2496   // f32 [1024]
#define SH_R2   3520   // u32 [128] reading f16 pairs
#define SH_D    3648   // f32 [32]
#define SH_G    3680   // f32 [32]
#define SH_RED  3712   // f32 [16]
#define SH_RED2 3728   // f32 [16]
#define SH_MISC 3744   // f32 [8]  [0]=beta
#define SH_B10  3752   // f32 [16]
#define SH_RA   3768   // f32 [8][64] reading_a partials
#define SH_CAND 4280   // u16[32*192] = 3072 f32 slots
#define SH_W    7352   // u16[32][1024] = 16384 f32 slots
#define SMEM_FLOATS 23736
#define SMEM_BYTES (SMEM_FLOATS*4)

#define WRED(v) { v += __shfl_xor(v,32); v += __shfl_xor(v,16); v += __shfl_xor(v,8); \
                  v += __shfl_xor(v,4);  v += __shfl_xor(v,2);  v += __shfl_xor(v,1); }

__device__ __forceinline__ f16x2 bch2(u32 u) { return __builtin_bit_cast(f16x2, u); }

#if __has_builtin(__builtin_amdgcn_fdot2)
__device__ __forceinline__ float FDOT2(u32 a, u32 b, float c) {
  return __builtin_amdgcn_fdot2(bch2(a), bch2(b), c, false);
}
#else
__device__ __forceinline__ float FDOT2(u32 a, u32 b, float c) {
  f16x2 x = bch2(a), y = bch2(b);
  return c + (float)x[0]*(float)y[0] + (float)x[1]*(float)y[1];
}
#endif

__device__ __forceinline__ u16 f2h(float x) {
  _Float16 h = (_Float16)x; return __builtin_bit_cast(u16, h);
}
__device__ __forceinline__ float h2f(u16 u) {
  return (float)__builtin_bit_cast(_Float16, u);
}
__device__ __forceinline__ u32 packh2(float lo, float hi) {
  return (u32)f2h(lo) | ((u32)f2h(hi) << 16);
}

// ---- k4-packed matvec: 1 out/lane. Wb: panel base (u32*), layout [k4][64] uint4.
// c2: LDS f16-pair coef (u32*), 16B aligned. Rolled loop + named 2-group pipeline:
// bounded ~45 VGPRs by construction (NO arrays -> no scratch).
template<int NK4>
__device__ __forceinline__ float mv_os4(const u32* __restrict__ Wb,
                                        const u32* __restrict__ c2, const int ln)
{
  const uint4* wp = (const uint4*)Wb + ln;
  const uint4* c4 = (const uint4*)c2;
  uint4 w0 = wp[0], w1 = wp[64];
  uint4 c0 = c4[0], c1 = c4[1];
  wp += 128;
  float a0 = 0.f, a1 = 0.f, a2 = 0.f, a3 = 0.f;
  #pragma unroll 1
  for (int it = 0; it < NK4/2 - 1; ++it) {
    const uint4 nw0 = wp[0], nw1 = wp[64];
    const uint4 nc0 = c4[2*it + 2], nc1 = c4[2*it + 3];
    wp += 128;
    a0 = FDOT2(w0.x, c0.x, a0);
    a1 = FDOT2(w0.y, c0.y, a1);
    a2 = FDOT2(w0.z, c0.z, a2);
    a3 = FDOT2(w0.w, c0.w, a3);
    a0 = FDOT2(w1.x, c1.x, a0);
    a1 = FDOT2(w1.y, c1.y, a1);
    a2 = FDOT2(w1.z, c1.z, a2);
    a3 = FDOT2(w1.w, c1.w, a3);
    w0 = nw0; w1 = nw1; c0 = nc0; c1 = nc1;
  }
  a0 = FDOT2(w0.x, c0.x, a0);
  a1 = FDOT2(w0.y, c0.y, a1);
  a2 = FDOT2(w0.z, c0.z, a2);
  a3 = FDOT2(w0.w, c0.w, a3);
  a0 = FDOT2(w1.x, c1.x, a0);
  a1 = FDOT2(w1.y, c1.y, a1);
  a2 = FDOT2(w1.z, c1.z, a2);
  a3 = FDOT2(w1.w, c1.w, a3);
  return (a0 + a1) + (a2 + a3);
}

__device__ __forceinline__ void out_lse(const float* __restrict__ b10,
    float* __restrict__ out, const int t_out, const int bb, const int ln)
{
  float v = (ln < 10) ? b10[ln] : -1e30f;
  float m = v;
  m = fmaxf(m, __shfl_xor(m, 8, 16));
  m = fmaxf(m, __shfl_xor(m, 4, 16));
  m = fmaxf(m, __shfl_xor(m, 2, 16));
  m = fmaxf(m, __shfl_xor(m, 1, 16));
  float e = (ln < 10) ? __expf(v - m) : 0.f;
  float s = e;
  s += __shfl_xor(s, 8, 16);
  s += __shfl_xor(s, 4, 16);
  s += __shfl_xor(s, 2, 16);
  s += __shfl_xor(s, 1, 16);
  if (ln < 10) out[262144 + t_out * 320 + ln * 32 + bb] = v - m - logf(s);
}

// ---------------- pack kernel ----------------
__device__ __forceinline__ void pack_panel(const float* __restrict__ srcA, int KA, int np4A,
                                           const float* __restrict__ srcB, int KB,
                                           int np4tot, int o0, u32* __restrict__ dstu, int tid)
{
  uint4* d4 = (uint4*)dstu;
  for (int idx = tid; idx < np4tot * 64; idx += 256) {
    const int k4 = idx >> 6, o = idx & 63;
    const float* s = (k4 < np4A) ? (srcA + (size_t)(o0 + o) * KA + k4 * 8)
                                 : (srcB + (size_t)(o0 + o) * KB + (k4 - np4A) * 8);
    uint4 v;
    v.x = packh2(s[0], s[1]); v.y = packh2(s[2], s[3]);
    v.z = packh2(s[4], s[5]); v.w = packh2(s[6], s[7]);
    d4[idx] = v;
  }
}

__global__ void pack_weights(const float* __restrict__ Wi, const float* __restrict__ Wh,
                             const float* __restrict__ Wm, const float* __restrict__ Wq,
                             const float* __restrict__ Wch, const float* __restrict__ Wci,
                             const float* __restrict__ maddr, const float* __restrict__ Wo,
                             u32* __restrict__ wsu)
{
  const int b = blockIdx.x, tid = threadIdx.x;
  if (b < 4)        pack_panel(Wh,          256, 32, Wi,        64, 40, b*64,      wsu + WP_A0  + b*10240, tid);
  else if (b < 8)   pack_panel(Wh + 65536,  256, 32, Wi + 16384,64, 40, (b-4)*64,  wsu + WP_A1  + (b-4)*10240, tid);
  else if (b < 12)  pack_panel(Wh + 131072, 256, 32, Wh,       256, 32, (b-8)*64,  wsu + WP_A2H + (b-8)*8192, tid);
  else if (b < 16)  pack_panel(Wi + 32768,   64,  8, Wi,        64,  8, (b-12)*64, wsu + WP_A2I + (b-12)*2048, tid);
  else if (b < 20)  pack_panel(Wq,          256, 32, Wq,       256, 32, (b-16)*64, wsu + WP_AQ  + (b-16)*8192, tid);
  else if (b < 23)  pack_panel(Wch,         256, 32, Wci,       64, 40, (b-20)*64, wsu + WP_AC  + (b-20)*10240, tid);
  else if (b < 35) { int x = b-23; int g = x>>2;
                    pack_panel(Wm + g*65536, 256, 32, Wm,      256, 32, (x&3)*64,  wsu + WP_AM  + x*8192, tid); }
  else if (b < 51)  pack_panel(maddr,        64,  8, maddr,     64,  8, (b-35)*64, wsu + WP_AT2 + (b-35)*2048, tid);
  else if (b < 55) { // M4: uint4(k4, a) = n-pairs 4k4..4k4+3 of maddr column a
    const int kb = b - 51;
    uint4* d4 = (uint4*)(wsu + WP_M4);
    for (int idx = tid; idx < 2048; idx += 256) {
      const int k4 = kb*32 + (idx >> 6), a = idx & 63;
      const float* s = maddr + (size_t)(8*k4)*64 + a;
      uint4 v;
      v.x = packh2(s[0],   s[64]);  v.y = packh2(s[128], s[192]);
      v.z = packh2(s[256], s[320]); v.w = packh2(s[384], s[448]);
      d4[k4*64 + a] = v;
    }
  } else {          // WO4: [10][32] uint4 = pack8(Wo[j][8l..8l+8])
    uint4* d4 = (uint4*)(wsu + WP_WO4);
    for (int idx = tid; idx < 320; idx += 256) {
      const int j = idx >> 5, l = idx & 31;
      const float* s = Wo + j*256 + l*8;
      uint4 v;
      v.x = packh2(s[0], s[1]); v.y = packh2(s[2], s[3]);
      v.z = packh2(s[4], s[5]); v.w = packh2(s[6], s[7]);
      d4[idx] = v;
    }
  }
}

// ---------------- main persistent per-batch kernel ----------------
__global__ __launch_bounds__(1024) void dntm_step(
    const float* __restrict__ batch, const float* __restrict__ bi,
    const float* __restrict__ bh, const float* __restrict__ bm,
    const float* __restrict__ bo, const float* __restrict__ bq,
    const float* __restrict__ usharp, const u32* __restrict__ wsu,
    float* __restrict__ out)
{
  extern __shared__ float sm[];
  u32* h2u   = (u32*)(sm + SH_H2);
  u32* Q2u   = (u32*)(sm + SH_Q2);
  u32* R2u   = (u32*)(sm + SH_R2);
  u16* candh = (u16*)(sm + SH_CAND);
  u16* SW16  = (u16*)(sm + SH_W);
  u32* SW32  = (u32*)(sm + SH_W);
  const int tid = threadIdx.x, ln = tid & 63, wv = tid >> 6;
  const int bb = blockIdx.x;

  if (tid < 256) sm[SH_HX + tid] = 0.f;
  if (tid < 128) h2u[tid] = 0u;
  if (tid >= 128 && tid < 160) {
    const int j = tid - 128;
    const int i0 = (2*j)*32 + bb, i1 = i0 + 32;
    const float x0 = batch[(i0 >> 6)*2048 + (i0 & 63)];
    const float x1 = batch[(i1 >> 6)*2048 + (i1 & 63)];
    h2u[128 + j] = packh2(x0, x1);
  }
  __syncthreads();

  for (int t = 0; t < 32; ++t) {
    // ============ P1: all h/x matvecs (f16 dot2, full-K panels) ============
    if (wv < 4) {
      sm[SH_GA0 + wv*64 + ln] = mv_os4<40>(wsu + WP_A0 + wv*10240, h2u, ln);
    } else if (wv < 8) {
      const int p = wv - 4;
      sm[SH_GA1 + p*64 + ln] = mv_os4<40>(wsu + WP_A1 + p*10240, h2u, ln);
    } else if (wv < 12) {
      const int p = wv - 8;
      sm[SH_GH2 + p*64 + ln] = mv_os4<32>(wsu + WP_A2H + p*8192, h2u, ln);
      sm[SH_GI2 + p*64 + ln] = mv_os4<8> (wsu + WP_A2I + p*2048, h2u + 128, ln);
    } else if (wv == 12) {
      const float qa = mv_os4<32>(wsu + WP_AQ,        h2u, ln) + bq[ln];
      const float qb = mv_os4<32>(wsu + WP_AQ + 8192, h2u, ln) + bq[64 + ln];
      sm[SH_Q + ln] = qa; sm[SH_Q + 64 + ln] = qb;
      const float rh = __shfl_down(qa, 1);
      if (!(ln & 1)) Q2u[ln >> 1] = packh2(qa, rh);
    } else if (wv == 13) {
      sm[SH_Q + 128 + ln] = mv_os4<32>(wsu + WP_AQ + 16384, h2u, ln) + bq[128 + ln];
      sm[SH_Q + 192 + ln] = mv_os4<32>(wsu + WP_AQ + 24576, h2u, ln) + bq[192 + ln];
    } else if (wv == 14) {
      candh[t*192 +      ln] = f2h(fmaxf(mv_os4<40>(wsu + WP_AC,         h2u, ln), 0.f));
      candh[t*192 + 64 + ln] = f2h(fmaxf(mv_os4<40>(wsu + WP_AC + 10240, h2u, ln), 0.f));
    } else {
      candh[t*192 + 128 + ln] = f2h(fmaxf(mv_os4<40>(wsu + WP_AC + 20480, h2u, ln), 0.f));
      { // beta = softplus(u.h) + 1  (f32)
        const float4 h4 = *(const float4*)(sm + SH_HX + ln*4);
        const float4 u4 = *(const float4*)(usharp + ln*4);
        float v = h4.x*u4.x + h4.y*u4.y + h4.z*u4.z + h4.w*u4.w;
        WRED(v);
        if (!ln) sm[SH_MISC] = fmaxf(v, 0.f) + log1pf(expf(-fabsf(v))) + 1.f;
      }
      if (t > 0) { // logits of h_t == h_new(t-1), f16 Wo x f16 h pairs
        const uint4 ch = ((const uint4*)h2u)[ln & 31];
        const uint4* wo4 = (const uint4*)(wsu + WP_WO4);
        for (int j = 0; j < 10; ++j) {
          float lv = 0.f;
          if (ln < 32) {
            const uint4 w4 = wo4[j*32 + ln];
            lv = FDOT2(w4.x, ch.x, lv); lv = FDOT2(w4.y, ch.y, lv);
            lv = FDOT2(w4.z, ch.z, lv); lv = FDOT2(w4.w, ch.w, lv);
          }
          WRED(lv);
          if (!ln) sm[SH_B10 + j] = lv + bo[j];
        }
      }
    }
    __syncthreads();

    // ===== P2: sim addr-part (f16 dot2); d[s] = cand_s . q_c; out_lse(t-1) =====
    if (wv < 8) {
      sm[SH_SIMA + wv*128 + ln]      = mv_os4<8>(wsu + WP_AT2 + (2*wv)*2048,   Q2u, ln);
      sm[SH_SIMA + wv*128 + 64 + ln] = mv_os4<8>(wsu + WP_AT2 + (2*wv+1)*2048, Q2u, ln);
    } else if (wv < 15) {
      const float q0 = sm[SH_Q + 64 + ln], q1 = sm[SH_Q + 128 + ln], q2 = sm[SH_Q + 192 + ln];
      for (int s = wv - 8; s < t; s += 7) {
        float a2 = h2f(candh[s*192 + ln]) * q0
                 + h2f(candh[s*192 + 64 + ln]) * q1
                 + h2f(candh[s*192 + 128 + ln]) * q2;
        WRED(a2);
        if (!ln) sm[SH_D + s] = a2;
      }
    } else {
      if (t > 0) out_lse(sm + SH_B10, out, t - 1, bb, ln);
    }
    __syncthreads();

    // ===== P3: v = beta*(sim_a + sum_s d[s] w_s[n]); wave max =====
    const int n3 = wv * 64 + ln;
    float v = sm[SH_SIMA + n3];
    #pragma unroll 4
    for (int s = 0; s < t; ++s) v = fmaf(sm[SH_D + s], h2f(SW16[s*1024 + n3]), v);
    v *= sm[SH_MISC];
    {
      float mx = v;
      mx = fmaxf(mx, __shfl_xor(mx, 32)); mx = fmaxf(mx, __shfl_xor(mx, 16));
      mx = fmaxf(mx, __shfl_xor(mx, 8));  mx = fmaxf(mx, __shfl_xor(mx, 4));
      mx = fmaxf(mx, __shfl_xor(mx, 2));  mx = fmaxf(mx, __shfl_xor(mx, 1));
      if (!ln) sm[SH_RED + wv] = mx;
    }
    __syncthreads();

    // ===== P4: e = exp(v - gmax) -> f16 history row t (unnormalized); wave sums =====
    {
      float gmx = sm[SH_RED];
      #pragma unroll
      for (int i = 1; i < 16; ++i) gmx = fmaxf(gmx, sm[SH_RED + i]);
      const float e = __expf(v - gmx);
      SW16[t*1024 + n3] = f2h(e);
      float s2 = e; WRED(s2);
      if (!ln) sm[SH_RED2 + wv] = s2;
    }
    __syncthreads();

    // ===== P5: reading_a partials (M4 k4-packed); g[s] = w_s . w_t =====
    {
      float tot = 0.f;
      #pragma unroll
      for (int i = 0; i < 16; ++i) tot += sm[SH_RED2 + i];
      const float inv = 1.0f / tot;
      if (wv < 8) {
        const float acc = mv_os4<16>(wsu + WP_M4 + wv*16*256,
                                     SW32 + t*512 + wv*64, ln);
        sm[SH_RA + wv*64 + ln] = acc * inv;
      } else {
        const uint4 ea = ((const uint4*)(SW32 + t*512))[ln*2];
        const uint4 eb = ((const uint4*)(SW32 + t*512))[ln*2 + 1];
        for (int s = wv - 8; s < t; s += 8) {
          const uint4 wa = ((const uint4*)(SW32 + s*512))[ln*2];
          const uint4 wb = ((const uint4*)(SW32 + s*512))[ln*2 + 1];
          float a2 = 0.f;
          a2 = FDOT2(ea.x, wa.x, a2); a2 = FDOT2(ea.y, wa.y, a2);
          a2 = FDOT2(ea.z, wa.z, a2); a2 = FDOT2(ea.w, wa.w, a2);
          a2 = FDOT2(eb.x, wb.x, a2); a2 = FDOT2(eb.y, wb.y, a2);
          a2 = FDOT2(eb.z, wb.z, a2); a2 = FDOT2(eb.w, wb.w, a2);
          WRED(a2);
          if (!ln) sm[SH_G + s] = a2 * inv;
        }
      }
    }
    __syncthreads();

    // ===== P6: assemble reading -> f16 pairs R2 =====
    if (wv == 0) {
      float r = 0.f;
      #pragma unroll
      for (int j = 0; j < 8; ++j) r += sm[SH_RA + j*64 + ln];
      const float rh = __shfl_down(r, 1);
      if (!(ln & 1)) R2u[ln >> 1] = packh2(r, rh);
    } else if (wv < 4) {
      const int c = (wv - 1)*64 + ln;
      float r = 0.f;
      for (int s = 0; s < t; ++s) r = fmaf(h2f(candh[s*192 + c]), sm[SH_G + s], r);
      const float rh = __shfl_down(r, 1);
      if (!(ln & 1)) R2u[wv*32 + (ln >> 1)] = packh2(r, rh);
    }
    __syncthreads();

    // ===== P7: gm = Wm @ reading (12 waves, full K); normalize w row; prefetch x =====
    if (wv < 12) {
      const int g = wv >> 2, p = wv & 3;
      sm[SH_GM + g*256 + p*64 + ln] = mv_os4<32>(wsu + WP_AM + wv*8192, R2u, ln);
    } else if (wv < 14) {
      float tot = 0.f;
      #pragma unroll
      for (int i = 0; i < 16; ++i) tot += sm[SH_RED2 + i];
      const float inv = 1.0f / tot;
      u32* p = SW32 + t*512 + (wv - 12)*256 + ln*4;
      uint4 v4 = *(const uint4*)p;
      v4.x = packh2(h2f(v4.x & 0xffff)*inv, h2f(v4.x >> 16)*inv);
      v4.y = packh2(h2f(v4.y & 0xffff)*inv, h2f(v4.y >> 16)*inv);
      v4.z = packh2(h2f(v4.z & 0xffff)*inv, h2f(v4.z >> 16)*inv);
      v4.w = packh2(h2f(v4.w & 0xffff)*inv, h2f(v4.w >> 16)*inv);
      *(uint4*)p = v4;
    } else if (wv == 14) {
      if (t < 31 && ln < 32) {
        const int i0 = (2*ln)*32 + bb, i1 = i0 + 32;
        const float x0 = batch[(i0 >> 6)*2048 + (t+1)*64 + (i0 & 63)];
        const float x1 = batch[(i1 >> 6)*2048 + (t+1)*64 + (i1 & 63)];
        h2u[128 + ln] = packh2(x0, x1);
      }
    }
    __syncthreads();

    // ===== P8: gate combine, h update, hs output, pack h pairs =====
    if (tid < 256) {
      const int h = tid;
      const float g0  = sm[SH_GA0 + h] + bi[h]       + bh[h]       + sm[SH_GM + h]       + bm[h];
      const float g1  = sm[SH_GA1 + h] + bi[256 + h] + bh[256 + h] + sm[SH_GM + 256 + h] + bm[256 + h];
      const float gh2v = sm[SH_GH2 + h] + bh[512 + h];
      const float gi2v = sm[SH_GI2 + h] + bi[512 + h];
      const float gm2  = sm[SH_GM + 512 + h] + bm[512 + h];
      const float r = 1.f / (1.f + __expf(-g0));
      const float z = 1.f / (1.f + __expf(-g1));
      const float nn = tanhf(gi2v + gm2 + r * gh2v);
      const float hn = (1.f - z) * nn + z * sm[SH_HX + h];
      sm[SH_HX + h] = hn;
      out[t*8192 + h*32 + bb] = hn;
      const float hn1 = __shfl_down(hn, 1);
      if (!(tid & 1)) h2u[tid >> 1] = packh2(hn, hn1);
    }
    __syncthreads();
  }

  // ---- epilogue: out[31] ----
  if (wv == 0) {
    const uint4 ch = ((const uint4*)h2u)[ln & 31];
    const uint4* wo4 = (const uint4*)(wsu + WP_WO4);
    for (int j = 0; j < 10; ++j) {
      float lv = 0.f;
      if (ln < 32) {
        const uint4 w4 = wo4[j*32 + ln];
        lv = FDOT2(w4.x, ch.x, lv); lv = FDOT2(w4.y, ch.y, lv);
        lv = FDOT2(w4.z, ch.z, lv); lv = FDOT2(w4.w, ch.w, lv);
      }
      WRED(lv);
      if (!ln) sm[SH_B10 + j] = lv + bo[j];
    }
    out_lse(sm + SH_B10, out, 31, bb, ln);
  }
}

extern "C" void kernel_launch(void* const* d_in, const int* in_sizes, int n_in,
                              void* d_out, int out_size, void* d_ws, size_t ws_size,
                              hipStream_t stream) {
  (void)in_sizes; (void)n_in; (void)out_size; (void)ws_size;
  const float* batch = (const float*)d_in[0];
  const float* Wi    = (const float*)d_in[1];
  const float* bi    = (const float*)d_in[2];
  const float* Wh    = (const float*)d_in[3];
  const float* bh    = (const float*)d_in[4];
  const float* Wm    = (const float*)d_in[5];
  const float* bm    = (const float*)d_in[6];
  const float* Wo    = (const float*)d_in[7];
  const float* bo    = (const float*)d_in[8];
  const float* maddr = (const float*)d_in[9];
  const float* Wq    = (const float*)d_in[10];
  const float* bq    = (const float*)d_in[11];
  const float* us    = (const float*)d_in[12];
  const float* Wch   = (const float*)d_in[13];
  const float* Wci   = (const float*)d_in[14];
  u32* wsu  = (u32*)d_ws;
  float* out = (float*)d_out;

  hipFuncSetAttribute((const void*)dntm_step,
                      hipFuncAttributeMaxDynamicSharedMemorySize, 163840);

  pack_weights<<<56, 256, 0, stream>>>(Wi, Wh, Wm, Wq, Wch, Wci, maddr, Wo, wsu);
  dntm_step<<<32, 1024, SMEM_BYTES, stream>>>(batch, bi, bh, bm, bo, bq, us, wsu, out);
}